// Round 11
// baseline (147.692 us; speedup 1.0000x reference)
//
#include <hip/hip_runtime.h>

// graph_56006373539875: per-edge spring-force scatter.
// R1: global f32 atomics -> 1881us. R2: LDS f32 redundant scan -> 240us.
// R3: de-gathered scan -> 238us. R4: bucket+f32 consume -> 340us.
// R5-R7: i64-packed consume + ballot/ring emit -> 144us (emit 110us).
// R8-R9: fused u64 scan -> 136us; latency wall at 16 waves/CU. Dead end.
// R10: lean emit (per-wave LDS-counter slot alloc + direct 8B stores)
//      -> 135.7us; emit 98us with VALU 10%, HBM 20%, occupancy 32%:
//      HALF the emit time is unhidden latency -- grid 4096 waves caps
//      at 16 waves/CU (50%), measured 32%. Pipe floors sum to ~45us.
// R11: NWAVE 8192 -> emit grid 1024 blocks = 4 blocks/CU = 32 waves/CU
//      (100% cap). Single-variable change for a clean occupancy read.

#define NR5    5
#define NWAVE  8192
#define K1T    1024              // count: 16 waves/block -> 512 blocks
#define EWAVES 8                 // emit: 8 waves/block -> 1024 blocks
#define K3T    (EWAVES * 64)
#define NBLD3  (NWAVE / EWAVES)
#define K4T    1024
#define NSLICE 44                // consume slices/range -> grid 220
#define QSCALE 4096.0f

struct __attribute__((packed, aligned(4))) F3 { float x, y, z; };

// ---------------- K1: per-WAVE per-range endpoint counts ------------------
__global__ __launch_bounds__(K1T) void count_kernel(
    const int* __restrict__ ea, const int* __restrict__ eb,
    unsigned* __restrict__ counts,           // [NR5][NWAVE]
    int n_edges, int chunk, unsigned magic)
{
    const int wid  = blockIdx.x * (K1T / 64) + ((int)threadIdx.x >> 6);
    const int lane = (int)threadIdx.x & 63;
    const int e0 = min(n_edges, wid * chunk);
    const int e1 = min(n_edges, e0 + chunk);
    const int nvec = (e1 - e0) & ~3;

    unsigned c[NR5];
#pragma unroll
    for (int j = 0; j < NR5; ++j) c[j] = 0;

    const int4* ea4 = (const int4*)(ea + e0);
    const int4* eb4 = (const int4*)(eb + e0);
    for (int g = lane; g < (nvec >> 2); g += 64) {
        int4 a4 = ea4[g];
        int4 b4 = eb4[g];
        unsigned r0 = __umulhi((unsigned)a4.x, magic), s0 = __umulhi((unsigned)b4.x, magic);
        unsigned r1 = __umulhi((unsigned)a4.y, magic), s1 = __umulhi((unsigned)b4.y, magic);
        unsigned r2 = __umulhi((unsigned)a4.z, magic), s2 = __umulhi((unsigned)b4.z, magic);
        unsigned r3 = __umulhi((unsigned)a4.w, magic), s3 = __umulhi((unsigned)b4.w, magic);
#pragma unroll
        for (int j = 0; j < NR5; ++j)
            c[j] += (r0 == (unsigned)j) + (s0 == (unsigned)j)
                  + (r1 == (unsigned)j) + (s1 == (unsigned)j)
                  + (r2 == (unsigned)j) + (s2 == (unsigned)j)
                  + (r3 == (unsigned)j) + (s3 == (unsigned)j);
    }
    for (int e = e0 + nvec + lane; e < e1; e += 64) {
        unsigned ra = __umulhi((unsigned)ea[e], magic);
        unsigned rb = __umulhi((unsigned)eb[e], magic);
#pragma unroll
        for (int j = 0; j < NR5; ++j)
            c[j] += (ra == (unsigned)j) + (rb == (unsigned)j);
    }
#pragma unroll
    for (int j = 0; j < NR5; ++j) {
        unsigned v = c[j];
#pragma unroll
        for (int off = 32; off > 0; off >>= 1) v += __shfl_down(v, off);
        if (lane == 0) counts[j * NWAVE + wid] = v;
    }
}

// ---------------- K2: exclusive prefix over waves, per range --------------
__global__ __launch_bounds__(NR5 * 64) void scan_kernel(
    const unsigned* __restrict__ counts,
    unsigned* __restrict__ waveprefix,
    unsigned* __restrict__ rangetotals)
{
    const int j    = (int)threadIdx.x >> 6;
    const int lane = (int)threadIdx.x & 63;
    unsigned running = 0;
    for (int c = 0; c < NWAVE / 64; ++c) {
        const int idx = c * 64 + lane;
        unsigned v = counts[j * NWAVE + idx];
        const unsigned orig = v;
#pragma unroll
        for (int off = 1; off < 64; off <<= 1) {
            unsigned t = __shfl_up(v, off);
            if (lane >= off) v += t;
        }
        waveprefix[j * NWAVE + idx] = running + v - orig;
        running += __shfl(v, 63);
    }
    if (lane == 0) rangetotals[j] = running;
}

// ---------------- K3: emit via LDS-counter slot alloc + direct store ------
__global__ __launch_bounds__(K3T) void emit_kernel(
    const float* __restrict__ points, const float* __restrict__ force,
    const int* __restrict__ ea, const int* __restrict__ eb,
    const unsigned* __restrict__ waveprefix, const unsigned* __restrict__ rangetotals,
    uint2* __restrict__ entries,             // [2*n_edges] {id|qx<<16, qy|qz<<16}
    int n_edges, int chunk, int range, unsigned magic)
{
    __shared__ unsigned cnt[EWAVES][NR5];
    const int wslot = (int)threadIdx.x >> 6;
    const int lane  = (int)threadIdx.x & 63;
    const int wid   = blockIdx.x * EWAVES + wslot;

    if (lane < NR5) {
        unsigned base = 0;
        for (int k = 0; k < lane; ++k) base += rangetotals[k];
        cnt[wslot][lane] = base + waveprefix[lane * NWAVE + wid];
    }
    __syncthreads();

    const F3* __restrict__ P = (const F3*)points;
    const int e0 = min(n_edges, wid * chunk);
    const int e1 = min(n_edges, e0 + chunk);
    const int nvec = (e1 - e0) & ~3;

    const int4*   ea4 = (const int4*)(ea + e0);
    const int4*   eb4 = (const int4*)(eb + e0);
    const float4* ff4 = (const float4*)(force + e0);

#define PROCE(pa, pb, fsc, aa, bb)                                               \
    {                                                                            \
        float vx = pb.x - pa.x, vy = pb.y - pa.y, vz = pb.z - pa.z;              \
        float s  = -(fsc) * rsqrtf(vx * vx + vy * vy + vz * vz);                 \
        int qx = __float2int_rn(s * vx * QSCALE);                                \
        int qy = __float2int_rn(s * vy * QSCALE);                                \
        int qz = __float2int_rn(s * vz * QSCALE);                                \
        qx = max(-32767, min(32767, qx));                                        \
        qy = max(-32767, min(32767, qy));                                        \
        qz = max(-32767, min(32767, qz));                                        \
        unsigned ra = __umulhi((unsigned)(aa), magic);                           \
        unsigned rb = __umulhi((unsigned)(bb), magic);                           \
        unsigned ida = (unsigned)(aa) - ra * (unsigned)range;                    \
        unsigned idb = (unsigned)(bb) - rb * (unsigned)range;                    \
        uint2 entA, entB;                                                        \
        entA.x = ida | ((unsigned)(unsigned short)(short)qx << 16);              \
        entA.y = (unsigned)(unsigned short)(short)qy                             \
               | ((unsigned)(unsigned short)(short)qz << 16);                    \
        entB.x = idb | ((unsigned)(unsigned short)(short)(-qx) << 16);           \
        entB.y = (unsigned)(unsigned short)(short)(-qy)                          \
               | ((unsigned)(unsigned short)(short)(-qz) << 16);                 \
        unsigned sA = atomicAdd(&cnt[wslot][ra], 1u);                            \
        entries[sA] = entA;                                                      \
        unsigned sB = atomicAdd(&cnt[wslot][rb], 1u);                            \
        entries[sB] = entB;                                                      \
    }

    for (int g = lane; g < (nvec >> 2); g += 64) {
        int4   a4 = ea4[g];
        int4   b4 = eb4[g];
        float4 f4 = ff4[g];
        // issue all 8 gathers before any math (MLP)
        F3 pa0 = P[a4.x]; F3 pb0 = P[b4.x];
        F3 pa1 = P[a4.y]; F3 pb1 = P[b4.y];
        F3 pa2 = P[a4.z]; F3 pb2 = P[b4.z];
        F3 pa3 = P[a4.w]; F3 pb3 = P[b4.w];
        PROCE(pa0, pb0, f4.x, a4.x, b4.x)
        PROCE(pa1, pb1, f4.y, a4.y, b4.y)
        PROCE(pa2, pb2, f4.z, a4.z, b4.z)
        PROCE(pa3, pb3, f4.w, a4.w, b4.w)
    }
    for (int e = e0 + nvec + lane; e < e1; e += 64) {
        int a = ea[e], b = eb[e];
        F3 pa = P[a], pb = P[b];
        float f = force[e];
        PROCE(pa, pb, f, a, b)
    }
#undef PROCE
}

// ---------------- K4: dense consume, ONE ds_add_u64 per entry -------------
__global__ __launch_bounds__(K4T) void consume_kernel(
    const ushort4* __restrict__ entries, const unsigned* __restrict__ rangetotals,
    unsigned long long* __restrict__ partial64,   // [NSLICE][np_pad]
    int np_pad, int range)
{
    extern __shared__ unsigned long long lds64[];   // [range]
    const int r     = blockIdx.x % NR5;
    const int slice = blockIdx.x / NR5;

    unsigned base = 0;
    for (int j = 0; j < r; ++j) base += rangetotals[j];
    const unsigned cnt = rangetotals[r];
    const unsigned lo = base + (unsigned)((unsigned long long)cnt * slice / NSLICE);
    const unsigned hi = base + (unsigned)((unsigned long long)cnt * (slice + 1) / NSLICE);

    for (int w = threadIdx.x; w < range; w += K4T) lds64[w] = 0ULL;
    __syncthreads();

    for (unsigned i = lo + threadIdx.x; i < hi; i += K4T) {
        ushort4 q = entries[i];
        long long v = (long long)(short)q.y
                    + ((long long)(short)q.z << 21)
                    + ((long long)(short)q.w << 42);
        atomicAdd(&lds64[q.x], (unsigned long long)v);
    }
    __syncthreads();

    unsigned long long* dst = partial64 + (size_t)slice * (size_t)np_pad
                            + (size_t)r * (size_t)range;
    for (int w = threadIdx.x; w < range; w += K4T) dst[w] = lds64[w];
}

// ---------------- K5: exact u64 reduce -> decode -> + ext -----------------
__global__ void reduce64_kernel(const float* __restrict__ ext,
                                const unsigned long long* __restrict__ partial64,
                                float* __restrict__ out, int n_points, int np_pad)
{
    int i = blockIdx.x * blockDim.x + threadIdx.x;
    if (i >= n_points) return;
    unsigned long long t = 0ULL;
#pragma unroll 4
    for (int c = 0; c < NSLICE; ++c)
        t += partial64[(size_t)c * (size_t)np_pad + i];

    long long T = (long long)t;
    long long X = ((long long)((unsigned long long)T << 43)) >> 43;
    T = (T - X) >> 21;
    long long Y = ((long long)((unsigned long long)T << 43)) >> 43;
    T = (T - Y) >> 21;
    long long Z = ((long long)((unsigned long long)T << 42)) >> 42;

    const float inv = 1.0f / QSCALE;
    out[3 * i + 0] = ext[3 * i + 0] + (float)X * inv;
    out[3 * i + 1] = ext[3 * i + 1] + (float)Y * inv;
    out[3 * i + 2] = ext[3 * i + 2] + (float)Z * inv;
}

// ---------------- fallback: fused scan with direct atomic flush -----------
#define NR_FB 8
#define NB_FB 32
#define BLOCK 1024
__global__ __launch_bounds__(BLOCK) void edge_scan_kernel(
    const float* __restrict__ points, const float* __restrict__ force,
    const int* __restrict__ ea, const int* __restrict__ eb,
    float* __restrict__ out,
    int n_edges, int n_points, int range)
{
    extern __shared__ float lds[];
    const int r = blockIdx.x / NB_FB;
    const int c = blockIdx.x % NB_FB;
    const int node0 = r * range;
    const int nwords = range * 3;
    for (int w = threadIdx.x; w < nwords; w += BLOCK) lds[w] = 0.0f;
    __syncthreads();
    const int chunk = (n_edges + NB_FB - 1) / NB_FB;
    const int e0 = c * chunk, e1 = min(n_edges, e0 + chunk);
    for (int e = e0 + (int)threadIdx.x; e < e1; e += BLOCK) {
        int a = ea[e], b = eb[e];
        int la = a - node0, lb = b - node0;
        bool ha = (unsigned)la < (unsigned)range;
        bool hb = (unsigned)lb < (unsigned)range;
        if (!(ha || hb)) continue;
        float ax = points[3*a], ay = points[3*a+1], az = points[3*a+2];
        float bx = points[3*b], by = points[3*b+1], bz = points[3*b+2];
        float vx = bx-ax, vy = by-ay, vz = bz-az;
        float s = -force[e] * rsqrtf(vx*vx+vy*vy+vz*vz);
        float fx = s*vx, fy = s*vy, fz = s*vz;
        if (ha) { atomicAdd(&lds[la*3+0], fx); atomicAdd(&lds[la*3+1], fy); atomicAdd(&lds[la*3+2], fz); }
        if (hb) { atomicAdd(&lds[lb*3+0], -fx); atomicAdd(&lds[lb*3+1], -fy); atomicAdd(&lds[lb*3+2], -fz); }
    }
    __syncthreads();
    const int basew = node0 * 3;
    const int total = n_points * 3;
    for (int w = threadIdx.x; w < nwords; w += BLOCK)
        if (basew + w < total) atomicAdd(&out[basew + w], lds[w]);
}

extern "C" void kernel_launch(void* const* d_in, const int* in_sizes, int n_in,
                              void* d_out, int out_size, void* d_ws, size_t ws_size,
                              hipStream_t stream) {
    const float* points = (const float*)d_in[0];
    const float* ext_f  = (const float*)d_in[1];
    const float* force  = (const float*)d_in[2];
    const int*   ea     = (const int*)d_in[3];
    const int*   eb     = (const int*)d_in[4];
    float* out = (float*)d_out;
    char*  ws  = (char*)d_ws;

    const int n_edges  = in_sizes[2];
    const int total    = out_size;                       // n_points*3
    const int n_points = total / 3;

    const int range5  = (n_points + NR5 - 1) / NR5;      // 20000
    const int np_pad  = range5 * NR5;
    const unsigned magic = (unsigned)((0x100000000ULL + range5 - 1) / (unsigned)range5);
    const int chunk = (((n_edges + NWAVE - 1) / NWAVE) + 3) & ~3;   // x4 aligned

    const size_t lds_consume = (size_t)range5 * sizeof(unsigned long long); // 160000
    const size_t entries_b = (size_t)2 * n_edges * sizeof(uint2);           // 102.4MB
    const size_t partial_b = (size_t)NSLICE * (size_t)np_pad * sizeof(unsigned long long); // 35.2MB
    const size_t cnt_b     = (size_t)NR5 * NWAVE * sizeof(unsigned);        // 160KB
    const size_t tail_need = (2 * cnt_b > partial_b) ? 2 * cnt_b : partial_b;
    const size_t need_new  = entries_b + tail_need + 64;

    const int range_fb = (n_points + NR_FB - 1) / NR_FB;
    const size_t lds_fb = (size_t)range_fb * 3 * sizeof(float);

    hipFuncSetAttribute((const void*)consume_kernel,
                        hipFuncAttributeMaxDynamicSharedMemorySize, (int)lds_consume);
    hipFuncSetAttribute((const void*)edge_scan_kernel,
                        hipFuncAttributeMaxDynamicSharedMemorySize, (int)lds_fb);

    if (range5 <= 0xFFFF && lds_consume <= 160 * 1024 && ws_size >= need_new) {
        uint2*    entries     = (uint2*)ws;
        unsigned long long* partial64 = (unsigned long long*)(ws + entries_b);
        unsigned* counts      = (unsigned*)(ws + entries_b);           // aliases partial64
        unsigned* waveprefix  = counts + (size_t)NR5 * NWAVE;
        unsigned* rangetotals = (unsigned*)(ws + ws_size - 64);        // survives K4

        count_kernel<<<NWAVE / (K1T / 64), K1T, 0, stream>>>(
            ea, eb, counts, n_edges, chunk, magic);
        scan_kernel<<<1, NR5 * 64, 0, stream>>>(counts, waveprefix, rangetotals);
        emit_kernel<<<NBLD3, K3T, 0, stream>>>(
            points, force, ea, eb, waveprefix, rangetotals, entries,
            n_edges, chunk, range5, magic);
        consume_kernel<<<NR5 * NSLICE, K4T, lds_consume, stream>>>(
            (const ushort4*)entries, rangetotals, partial64, np_pad, range5);
        const int rb = 256;
        reduce64_kernel<<<(n_points + rb - 1) / rb, rb, 0, stream>>>(
            ext_f, partial64, out, n_points, np_pad);
    } else {
        hipMemcpyAsync(d_out, (const void*)ext_f, (size_t)total * sizeof(float),
                       hipMemcpyDeviceToDevice, stream);
        edge_scan_kernel<<<NR_FB * NB_FB, BLOCK, lds_fb, stream>>>(
            points, force, ea, eb, out, n_edges, n_points, range_fb);
    }
}